// Round 1
// baseline (30.079 us; speedup 1.0000x reference)
//
#include <hip/hip_runtime.h>

#define NROW 48
#define WCOL 16
#define XDIM 256
#define NW   768   // NROW*WCOL

// One block per row n. 256 threads.
__global__ __launch_bounds__(256) void triplet_row_kernel(
    const float* __restrict__ emb,   // (48,16,256) f32
    const float* __restrict__ lab,   // (48,16) f32
    float* __restrict__ out,         // 337 f32
    float* __restrict__ ws)          // >= 96 f32: [0..47]=tsum, [48..95]=thard
{
    const int n   = blockIdx.x;
    const int tid = threadIdx.x;

    __shared__ __align__(16) float a_s[XDIM];
    __shared__ float dist_s[NW];
    __shared__ float lab_s[WCOL];
    __shared__ float pd_s[WCOL];
    __shared__ int   pmask_s[WCOL];
    __shared__ float aa_s;
    __shared__ float red_f[4];

    // ---- stage anchor + labels ----
    a_s[tid] = emb[(n * WCOL + 0) * XDIM + tid];
    if (tid < WCOL) lab_s[tid] = lab[n * WCOL + tid];
    __syncthreads();

    // ---- aa = sum(a*a) (block reduce) ----
    {
        float v = a_s[tid];
        float p = v * v;
        for (int o = 32; o; o >>= 1) p += __shfl_down(p, o, 64);
        if ((tid & 63) == 0) red_f[tid >> 6] = p;
        __syncthreads();
        if (tid == 0) aa_s = red_f[0] + red_f[1] + red_f[2] + red_f[3];
        __syncthreads();
    }
    const float aa = aa_s;

    // ---- dist[m] for m=0..767: 16 lanes per column, 16 columns in flight ----
    {
        const int grp = tid >> 4;   // 0..15 (aligned to 16-lane segments of the wave)
        const int l   = tid & 15;   // 0..15
        for (int m = grp; m < NW; m += 16) {
            const float* col = emb + m * XDIM;
            float dot = 0.f, bb = 0.f;
            #pragma unroll
            for (int k = 0; k < 4; ++k) {
                float4 b4 = *(const float4*)(col + k * 64 + l * 4);
                float4 a4 = *(const float4*)(&a_s[k * 64 + l * 4]);
                dot += a4.x * b4.x + a4.y * b4.y + a4.z * b4.z + a4.w * b4.w;
                bb  += b4.x * b4.x + b4.y * b4.y + b4.z * b4.z + b4.w * b4.w;
            }
            for (int o = 8; o; o >>= 1) {
                dot += __shfl_down(dot, o, 16);
                bb  += __shfl_down(bb,  o, 16);
            }
            if (l == 0) {
                float d = aa - 2.f * dot + bb;
                dist_s[m] = d > 0.f ? d : 0.f;   // relu
            }
        }
    }
    __syncthreads();

    // ---- positive info for this row ----
    if (tid < WCOL) {
        pd_s[tid]    = dist_s[n * WCOL + tid];
        pmask_s[tid] = (lab_s[tid] > 0.5f) ? 1 : 0;
    }
    __syncthreads();

    // ---- per-thread scan over negatives (3 columns each) ----
    float minv = 1e30f; int mini = NW;    // min dist over negatives, first index
    float sum_neg = 0.f; int cnt_neg = 0;
    int   accu_cnt = 0;
    float tsum = 0.f;  int thard = 0;

    for (int m = tid; m < NW; m += 256) {
        const bool own = ((m >> 4) == n);
        const int  w   = m & 15;
        const bool is_neg = own ? !(pmask_s[w] || w == 0) : true;
        if (is_neg) {
            const float dm = dist_s[m];
            sum_neg += dm;
            cnt_neg += 1;
            if (dm < minv) { minv = dm; mini = m; }  // ascending m per thread -> first kept
            #pragma unroll
            for (int j = 0; j < WCOL; ++j) {
                if (pmask_s[j]) {
                    const float pj = pd_s[j];
                    accu_cnt += (dm > pj) ? 1 : 0;           // diff = dist[i]-dist[j] > 0
                    const float tv = pj - dm + 1.0f;         // (diff + MARGIN), i=pos j=neg
                    if (tv > 0.f) {
                        tsum  += tv;
                        thard += (tv > 1e-16f) ? 1 : 0;
                    }
                }
            }
        }
    }

    // ---- block reduction ----
    for (int o = 32; o; o >>= 1) {
        float ov = __shfl_down(minv, o, 64);
        int   oi = __shfl_down(mini, o, 64);
        if (ov < minv || (ov == minv && oi < mini)) { minv = ov; mini = oi; }
        sum_neg  += __shfl_down(sum_neg,  o, 64);
        cnt_neg  += __shfl_down(cnt_neg,  o, 64);
        accu_cnt += __shfl_down(accu_cnt, o, 64);
        tsum     += __shfl_down(tsum,     o, 64);
        thard    += __shfl_down(thard,    o, 64);
    }

    __shared__ float wminv[4], wsum[4], wtsum[4];
    __shared__ int   wmini[4], wcnt[4], waccu[4], wthard[4];
    const int wid = tid >> 6;
    if ((tid & 63) == 0) {
        wminv[wid] = minv;  wmini[wid] = mini;
        wsum[wid]  = sum_neg; wcnt[wid] = cnt_neg;
        waccu[wid] = accu_cnt; wtsum[wid] = tsum; wthard[wid] = thard;
    }
    __syncthreads();

    if (tid == 0) {
        minv = wminv[0]; mini = wmini[0];
        sum_neg = wsum[0]; cnt_neg = wcnt[0];
        accu_cnt = waccu[0]; tsum = wtsum[0]; thard = wthard[0];
        for (int q = 1; q < 4; ++q) {
            if (wminv[q] < minv || (wminv[q] == minv && wmini[q] < mini)) {
                minv = wminv[q]; mini = wmini[q];
            }
            sum_neg += wsum[q]; cnt_neg += wcnt[q];
            accu_cnt += waccu[q]; tsum += wtsum[q]; thard += wthard[q];
        }

        // positive stats (<=16 values), strict > keeps first index for argmax
        float maxp = -1e30f; int maxj = -1;
        float sum_pos = 0.f; int num_pos = 0;
        for (int w = 0; w < WCOL; ++w) {
            if (pmask_s[w]) {
                const float pv = pd_s[w];
                sum_pos += pv; num_pos += 1;
                if (pv > maxp) { maxp = pv; maxj = w; }
            }
        }

        const float fnum_pos = (float)num_pos;
        const float fnum_neg = (float)cnt_neg;
        const float n_pairs  = fnum_pos * fnum_neg;

        // neg_idx: cumsum(negm)[mini] - 1 = (mini+1) - (#Pext<=mini in own block) - 1
        int pext_le = 0;
        for (int w = 0; w < WCOL; ++w) {
            const int col = n * WCOL + w;
            if (col <= mini && (pmask_s[w] || w == 0)) pext_le++;
        }
        const float neg_idx = (float)(mini + 1 - pext_le) - 1.0f;

        // pos_idx: cumsum(P)[j_full] - 1 (rank among positives)
        int pos_le = 0;
        for (int w = 0; w <= maxj; ++w) pos_le += pmask_s[w];
        const float pos_idx = (float)pos_le - 1.0f;

        const float avg_n2p = (fnum_pos * sum_neg - fnum_neg * sum_pos) / n_pairs;

        out[1         + n] = maxp;                 // max_anchor2pos
        out[1 +  48   + n] = minv;                 // min_anchor2neg
        out[1 +  96   + n] = minv - maxp;          // min_neg2pos
        out[1 + 144   + n] = avg_n2p;              // avg_neg2pos
        out[1 + 192   + n] = neg_idx;              // neg_idx
        out[1 + 240   + n] = pos_idx;              // pos_idx
        out[1 + 288   + n] = (float)accu_cnt / n_pairs; // accu_ratio

        ws[n]        = tsum;
        ws[48 + n]   = (float)thard;
    }
}

__global__ __launch_bounds__(64) void triplet_finalize_kernel(
    const float* __restrict__ ws, float* __restrict__ out)
{
    const int t = threadIdx.x;
    float s = (t < NROW) ? ws[t]       : 0.f;
    float c = (t < NROW) ? ws[48 + t]  : 0.f;
    for (int o = 32; o; o >>= 1) {
        s += __shfl_down(s, o, 64);
        c += __shfl_down(c, o, 64);
    }
    if (t == 0) out[0] = s / (c + 1e-16f);
}

extern "C" void kernel_launch(void* const* d_in, const int* in_sizes, int n_in,
                              void* d_out, int out_size, void* d_ws, size_t ws_size,
                              hipStream_t stream) {
    const float* emb = (const float*)d_in[0];
    const float* lab = (const float*)d_in[1];
    float* out = (float*)d_out;
    float* ws  = (float*)d_ws;

    hipLaunchKernelGGL(triplet_row_kernel, dim3(NROW), dim3(256), 0, stream,
                       emb, lab, out, ws);
    hipLaunchKernelGGL(triplet_finalize_kernel, dim3(1), dim3(64), 0, stream,
                       ws, out);
}

// Round 2
// 18.454 us; speedup vs baseline: 1.6300x; 1.6300x over previous
//
#include <hip/hip_runtime.h>

#define NROW 48
#define WCOL 16
#define XDIM 256
#define NW   768   // NROW*WCOL

// ws float layout (fast path)
#define WS_DIST 0            // 48*768 floats
#define WS_TS   (NW * NROW)  // 36864: 48 floats tsum
#define WS_TH   (WS_TS + 48) // 48 floats thard
#define WS_CTR  (WS_TH + 48) // 1 uint
#define WS_NEED ((size_t)(WS_CTR + 4) * 4)

// ---------------- fast path: kernel 1 — dist matrix ----------------
// grid = 48 rows * 16 slices = 768 blocks, 256 threads.
// Each block computes 48 columns of dist for one row. No LDS, no syncs.
__global__ __launch_bounds__(256) void dist_kernel(
    const float* __restrict__ emb, float* __restrict__ ws)
{
    const int bid = blockIdx.x;
    const int n   = bid >> 4;        // row
    const int s   = bid & 15;        // slice
    const int tid = threadIdx.x;
    const int grp = tid >> 4;        // 0..15, aligned 16-lane segments
    const int l   = tid & 15;

    if (bid == 0 && tid == 0) {
        __hip_atomic_store((unsigned*)(ws + WS_CTR), 0u,
                           __ATOMIC_RELAXED, __HIP_MEMORY_SCOPE_AGENT);
    }

    const float* anchor = emb + n * (WCOL * XDIM);  // ANCHOR_IDX = 0
    float4 a[4];
    float paa = 0.f;
    #pragma unroll
    for (int k = 0; k < 4; ++k) {
        a[k] = *(const float4*)(anchor + k * 64 + l * 4);
        paa += a[k].x * a[k].x + a[k].y * a[k].y + a[k].z * a[k].z + a[k].w * a[k].w;
    }
    float aa = paa;
    for (int o = 8; o; o >>= 1) aa += __shfl_down(aa, o, 16);  // lane l==0 holds aa

    #pragma unroll
    for (int it = 0; it < 3; ++it) {
        const int m = s * 48 + it * 16 + grp;
        const float* col = emb + m * XDIM;
        float pdot = 0.f, pbb = 0.f;
        #pragma unroll
        for (int k = 0; k < 4; ++k) {
            float4 b = *(const float4*)(col + k * 64 + l * 4);
            pdot += a[k].x * b.x + a[k].y * b.y + a[k].z * b.z + a[k].w * b.w;
            pbb  += b.x * b.x + b.y * b.y + b.z * b.z + b.w * b.w;
        }
        for (int o = 8; o; o >>= 1) {
            pdot += __shfl_down(pdot, o, 16);
            pbb  += __shfl_down(pbb,  o, 16);
        }
        if (l == 0) {
            float d = aa - 2.f * pdot + pbb;
            ws[WS_DIST + n * NW + m] = d > 0.f ? d : 0.f;   // relu
        }
    }
}

// ---------------- fast path: kernel 2 — per-row stats + fused finalize ----
__global__ __launch_bounds__(256) void row_stats_kernel(
    const float* __restrict__ lab, float* __restrict__ out,
    float* __restrict__ ws)
{
    const int n   = blockIdx.x;
    const int tid = threadIdx.x;

    __shared__ float dist_s[NW];
    __shared__ float pd_s[WCOL];
    __shared__ int   pmask_s[WCOL];
    __shared__ int   last_s;

    for (int i = tid; i < NW; i += 256) dist_s[i] = ws[WS_DIST + n * NW + i];
    __syncthreads();
    if (tid < WCOL) {
        pd_s[tid]    = dist_s[n * WCOL + tid];
        pmask_s[tid] = (lab[n * WCOL + tid] > 0.5f) ? 1 : 0;
    }
    __syncthreads();

    // per-thread scan over negatives (3 columns each)
    float minv = 1e30f; int mini = NW;
    float sum_neg = 0.f; int cnt_neg = 0;
    int   accu_cnt = 0;
    float tsum = 0.f;  int thard = 0;

    for (int m = tid; m < NW; m += 256) {
        const bool own = ((m >> 4) == n);
        const int  w   = m & 15;
        const bool is_neg = own ? !(pmask_s[w] || w == 0) : true;
        if (is_neg) {
            const float dm = dist_s[m];
            sum_neg += dm;
            cnt_neg += 1;
            if (dm < minv) { minv = dm; mini = m; }
            #pragma unroll
            for (int j = 0; j < WCOL; ++j) {
                if (pmask_s[j]) {
                    const float pj = pd_s[j];
                    accu_cnt += (dm > pj) ? 1 : 0;
                    const float tv = pj - dm + 1.0f;
                    if (tv > 0.f) {
                        tsum  += tv;
                        thard += (tv > 1e-16f) ? 1 : 0;
                    }
                }
            }
        }
    }

    for (int o = 32; o; o >>= 1) {
        float ov = __shfl_down(minv, o, 64);
        int   oi = __shfl_down(mini, o, 64);
        if (ov < minv || (ov == minv && oi < mini)) { minv = ov; mini = oi; }
        sum_neg  += __shfl_down(sum_neg,  o, 64);
        cnt_neg  += __shfl_down(cnt_neg,  o, 64);
        accu_cnt += __shfl_down(accu_cnt, o, 64);
        tsum     += __shfl_down(tsum,     o, 64);
        thard    += __shfl_down(thard,    o, 64);
    }

    __shared__ float wminv[4], wsum[4], wtsum[4];
    __shared__ int   wmini[4], wcnt[4], waccu[4], wthard[4];
    const int wid = tid >> 6;
    if ((tid & 63) == 0) {
        wminv[wid] = minv;  wmini[wid] = mini;
        wsum[wid]  = sum_neg; wcnt[wid] = cnt_neg;
        waccu[wid] = accu_cnt; wtsum[wid] = tsum; wthard[wid] = thard;
    }
    __syncthreads();

    if (tid == 0) {
        minv = wminv[0]; mini = wmini[0];
        sum_neg = wsum[0]; cnt_neg = wcnt[0];
        accu_cnt = waccu[0]; tsum = wtsum[0]; thard = wthard[0];
        for (int q = 1; q < 4; ++q) {
            if (wminv[q] < minv || (wminv[q] == minv && wmini[q] < mini)) {
                minv = wminv[q]; mini = wmini[q];
            }
            sum_neg += wsum[q]; cnt_neg += wcnt[q];
            accu_cnt += waccu[q]; tsum += wtsum[q]; thard += wthard[q];
        }

        float maxp = -1e30f; int maxj = -1;
        float sum_pos = 0.f; int num_pos = 0;
        for (int w = 0; w < WCOL; ++w) {
            if (pmask_s[w]) {
                const float pv = pd_s[w];
                sum_pos += pv; num_pos += 1;
                if (pv > maxp) { maxp = pv; maxj = w; }
            }
        }

        const float fnum_pos = (float)num_pos;
        const float fnum_neg = (float)cnt_neg;
        const float n_pairs  = fnum_pos * fnum_neg;

        int pext_le = 0;
        for (int w = 0; w < WCOL; ++w) {
            const int col = n * WCOL + w;
            if (col <= mini && (pmask_s[w] || w == 0)) pext_le++;
        }
        const float neg_idx = (float)(mini + 1 - pext_le) - 1.0f;

        int pos_le = 0;
        for (int w = 0; w <= maxj; ++w) pos_le += pmask_s[w];
        const float pos_idx = (float)pos_le - 1.0f;

        const float avg_n2p = (fnum_pos * sum_neg - fnum_neg * sum_pos) / n_pairs;

        out[1         + n] = maxp;
        out[1 +  48   + n] = minv;
        out[1 +  96   + n] = minv - maxp;
        out[1 + 144   + n] = avg_n2p;
        out[1 + 192   + n] = neg_idx;
        out[1 + 240   + n] = pos_idx;
        out[1 + 288   + n] = (float)accu_cnt / n_pairs;

        __hip_atomic_store(&ws[WS_TS + n], tsum,
                           __ATOMIC_RELAXED, __HIP_MEMORY_SCOPE_AGENT);
        __hip_atomic_store(&ws[WS_TH + n], (float)thard,
                           __ATOMIC_RELAXED, __HIP_MEMORY_SCOPE_AGENT);
        __threadfence();
        unsigned old = __hip_atomic_fetch_add((unsigned*)(ws + WS_CTR), 1u,
                                              __ATOMIC_ACQ_REL, __HIP_MEMORY_SCOPE_AGENT);
        last_s = (old == NROW - 1) ? 1 : 0;
    }
    __syncthreads();

    // last block to finish: deterministic fixed-order finalize on one wave
    if (last_s && tid < 64) {
        __threadfence();
        float s = 0.f, c = 0.f;
        if (tid < NROW) {
            s = __hip_atomic_load(&ws[WS_TS + tid], __ATOMIC_RELAXED, __HIP_MEMORY_SCOPE_AGENT);
            c = __hip_atomic_load(&ws[WS_TH + tid], __ATOMIC_RELAXED, __HIP_MEMORY_SCOPE_AGENT);
        }
        for (int o = 32; o; o >>= 1) {
            s += __shfl_down(s, o, 64);
            c += __shfl_down(c, o, 64);
        }
        if (tid == 0) out[0] = s / (c + 1e-16f);
    }
}

// ---------------- fallback path (round-1 proven kernel) ----------------
__global__ __launch_bounds__(256) void triplet_row_kernel(
    const float* __restrict__ emb, const float* __restrict__ lab,
    float* __restrict__ out, float* __restrict__ ws)
{
    const int n   = blockIdx.x;
    const int tid = threadIdx.x;

    __shared__ __align__(16) float a_s[XDIM];
    __shared__ float dist_s[NW];
    __shared__ float lab_s[WCOL];
    __shared__ float pd_s[WCOL];
    __shared__ int   pmask_s[WCOL];
    __shared__ float aa_s;
    __shared__ float red_f[4];

    a_s[tid] = emb[(n * WCOL + 0) * XDIM + tid];
    if (tid < WCOL) lab_s[tid] = lab[n * WCOL + tid];
    __syncthreads();

    {
        float v = a_s[tid];
        float p = v * v;
        for (int o = 32; o; o >>= 1) p += __shfl_down(p, o, 64);
        if ((tid & 63) == 0) red_f[tid >> 6] = p;
        __syncthreads();
        if (tid == 0) aa_s = red_f[0] + red_f[1] + red_f[2] + red_f[3];
        __syncthreads();
    }
    const float aa = aa_s;

    {
        const int grp = tid >> 4;
        const int l   = tid & 15;
        for (int m = grp; m < NW; m += 16) {
            const float* col = emb + m * XDIM;
            float dot = 0.f, bb = 0.f;
            #pragma unroll
            for (int k = 0; k < 4; ++k) {
                float4 b4 = *(const float4*)(col + k * 64 + l * 4);
                float4 a4 = *(const float4*)(&a_s[k * 64 + l * 4]);
                dot += a4.x * b4.x + a4.y * b4.y + a4.z * b4.z + a4.w * b4.w;
                bb  += b4.x * b4.x + b4.y * b4.y + b4.z * b4.z + b4.w * b4.w;
            }
            for (int o = 8; o; o >>= 1) {
                dot += __shfl_down(dot, o, 16);
                bb  += __shfl_down(bb,  o, 16);
            }
            if (l == 0) {
                float d = aa - 2.f * dot + bb;
                dist_s[m] = d > 0.f ? d : 0.f;
            }
        }
    }
    __syncthreads();

    if (tid < WCOL) {
        pd_s[tid]    = dist_s[n * WCOL + tid];
        pmask_s[tid] = (lab_s[tid] > 0.5f) ? 1 : 0;
    }
    __syncthreads();

    float minv = 1e30f; int mini = NW;
    float sum_neg = 0.f; int cnt_neg = 0;
    int   accu_cnt = 0;
    float tsum = 0.f;  int thard = 0;

    for (int m = tid; m < NW; m += 256) {
        const bool own = ((m >> 4) == n);
        const int  w   = m & 15;
        const bool is_neg = own ? !(pmask_s[w] || w == 0) : true;
        if (is_neg) {
            const float dm = dist_s[m];
            sum_neg += dm;
            cnt_neg += 1;
            if (dm < minv) { minv = dm; mini = m; }
            #pragma unroll
            for (int j = 0; j < WCOL; ++j) {
                if (pmask_s[j]) {
                    const float pj = pd_s[j];
                    accu_cnt += (dm > pj) ? 1 : 0;
                    const float tv = pj - dm + 1.0f;
                    if (tv > 0.f) {
                        tsum  += tv;
                        thard += (tv > 1e-16f) ? 1 : 0;
                    }
                }
            }
        }
    }

    for (int o = 32; o; o >>= 1) {
        float ov = __shfl_down(minv, o, 64);
        int   oi = __shfl_down(mini, o, 64);
        if (ov < minv || (ov == minv && oi < mini)) { minv = ov; mini = oi; }
        sum_neg  += __shfl_down(sum_neg,  o, 64);
        cnt_neg  += __shfl_down(cnt_neg,  o, 64);
        accu_cnt += __shfl_down(accu_cnt, o, 64);
        tsum     += __shfl_down(tsum,     o, 64);
        thard    += __shfl_down(thard,    o, 64);
    }

    __shared__ float wminv[4], wsum[4], wtsum[4];
    __shared__ int   wmini[4], wcnt[4], waccu[4], wthard[4];
    const int wid = tid >> 6;
    if ((tid & 63) == 0) {
        wminv[wid] = minv;  wmini[wid] = mini;
        wsum[wid]  = sum_neg; wcnt[wid] = cnt_neg;
        waccu[wid] = accu_cnt; wtsum[wid] = tsum; wthard[wid] = thard;
    }
    __syncthreads();

    if (tid == 0) {
        minv = wminv[0]; mini = wmini[0];
        sum_neg = wsum[0]; cnt_neg = wcnt[0];
        accu_cnt = waccu[0]; tsum = wtsum[0]; thard = wthard[0];
        for (int q = 1; q < 4; ++q) {
            if (wminv[q] < minv || (wminv[q] == minv && wmini[q] < mini)) {
                minv = wminv[q]; mini = wmini[q];
            }
            sum_neg += wsum[q]; cnt_neg += wcnt[q];
            accu_cnt += waccu[q]; tsum += wtsum[q]; thard += wthard[q];
        }

        float maxp = -1e30f; int maxj = -1;
        float sum_pos = 0.f; int num_pos = 0;
        for (int w = 0; w < WCOL; ++w) {
            if (pmask_s[w]) {
                const float pv = pd_s[w];
                sum_pos += pv; num_pos += 1;
                if (pv > maxp) { maxp = pv; maxj = w; }
            }
        }

        const float fnum_pos = (float)num_pos;
        const float fnum_neg = (float)cnt_neg;
        const float n_pairs  = fnum_pos * fnum_neg;

        int pext_le = 0;
        for (int w = 0; w < WCOL; ++w) {
            const int col = n * WCOL + w;
            if (col <= mini && (pmask_s[w] || w == 0)) pext_le++;
        }
        const float neg_idx = (float)(mini + 1 - pext_le) - 1.0f;

        int pos_le = 0;
        for (int w = 0; w <= maxj; ++w) pos_le += pmask_s[w];
        const float pos_idx = (float)pos_le - 1.0f;

        const float avg_n2p = (fnum_pos * sum_neg - fnum_neg * sum_pos) / n_pairs;

        out[1         + n] = maxp;
        out[1 +  48   + n] = minv;
        out[1 +  96   + n] = minv - maxp;
        out[1 + 144   + n] = avg_n2p;
        out[1 + 192   + n] = neg_idx;
        out[1 + 240   + n] = pos_idx;
        out[1 + 288   + n] = (float)accu_cnt / n_pairs;

        ws[n]      = tsum;
        ws[48 + n] = (float)thard;
    }
}

__global__ __launch_bounds__(64) void triplet_finalize_kernel(
    const float* __restrict__ ws, float* __restrict__ out)
{
    const int t = threadIdx.x;
    float s = (t < NROW) ? ws[t]      : 0.f;
    float c = (t < NROW) ? ws[48 + t] : 0.f;
    for (int o = 32; o; o >>= 1) {
        s += __shfl_down(s, o, 64);
        c += __shfl_down(c, o, 64);
    }
    if (t == 0) out[0] = s / (c + 1e-16f);
}

extern "C" void kernel_launch(void* const* d_in, const int* in_sizes, int n_in,
                              void* d_out, int out_size, void* d_ws, size_t ws_size,
                              hipStream_t stream) {
    const float* emb = (const float*)d_in[0];
    const float* lab = (const float*)d_in[1];
    float* out = (float*)d_out;
    float* ws  = (float*)d_ws;

    if (ws_size >= WS_NEED) {
        hipLaunchKernelGGL(dist_kernel, dim3(NROW * 16), dim3(256), 0, stream,
                           emb, ws);
        hipLaunchKernelGGL(row_stats_kernel, dim3(NROW), dim3(256), 0, stream,
                           lab, out, ws);
    } else {
        hipLaunchKernelGGL(triplet_row_kernel, dim3(NROW), dim3(256), 0, stream,
                           emb, lab, out, ws);
        hipLaunchKernelGGL(triplet_finalize_kernel, dim3(1), dim3(64), 0, stream,
                           ws, out);
    }
}